// Round 8
// baseline (5690.085 us; speedup 1.0000x reference)
//
#include <hip/hip_runtime.h>

#define NB 32
#define NM 128
#define NL 32
#define NH 512
#define NV 32000
#define NHOPS 3
#define NEG_INF -1e9f

#define VC_U 128
#define NPART (NV / VC_U)       // 250 split-K partials

// Diagnostic: in-kernel repetition factor to lift per-kernel durations above
// the harness fill-kernel floor (~150us) so they appear in rocprof top-5.
// Outputs are idempotent across reps; non-idempotent side effects are outside
// the rep region. Divide observed dur_us by REP for true cost.
#define REP 16

typedef __attribute__((ext_vector_type(8))) short bf16x8;
typedef __attribute__((ext_vector_type(4))) float f32x4;

__device__ __forceinline__ unsigned short f2bf(float x) {
    unsigned u = __float_as_uint(x);
    return (unsigned short)((u + 0x7fffu + ((u >> 16) & 1u)) >> 16);
}
__device__ __forceinline__ float bf2f(unsigned short h) {
    return __uint_as_float(((unsigned)h) << 16);
}

// ---------------------------------------------------------------------------
// init: zero w; split enc -> uh/ul. grid 256 x 256.
// ---------------------------------------------------------------------------
__global__ __launch_bounds__(256)
void init_kernel(const float* __restrict__ enc, float* __restrict__ w,
                 unsigned short* __restrict__ uh, unsigned short* __restrict__ ul) {
    const int gtid = blockIdx.x * 256 + threadIdx.x;     // 65536 threads
    float4* w4 = reinterpret_cast<float4*>(w);
    for (int i = gtid; i < (NB * NV) / 4; i += 256 * 256)
        w4[i] = make_float4(0.f, 0.f, 0.f, 0.f);
    if (gtid < NB * NH) {
        const float x = enc[gtid];
        const unsigned short h = f2bf(x);
        uh[gtid] = h;
        ul[gtid] = f2bf(x - bf2f(h));
    }
}

// ---------------------------------------------------------------------------
// gemm_D: D[b][v] = u[b].C[v]  (M=32, N=32000, K=512), split-bf16, NO LDS.
// ---------------------------------------------------------------------------
__global__ __launch_bounds__(256)
void gemm_D_kernel(const unsigned short* __restrict__ uh,
                   const unsigned short* __restrict__ ul,
                   const float* __restrict__ Ct,
                   float* __restrict__ D) {
    const int tid = threadIdx.x;
    const int wv = tid >> 6, lane = tid & 63;
    const int n = lane & 15;
    const int kblk = (lane >> 4) << 3;
    const int vrow = (blockIdx.x * 4 + wv) * 16 + n;

    const float* Crow = Ct + ((size_t)vrow << 9) + kblk;
    const unsigned short* ua0 = uh + (n << 9) + kblk;
    const unsigned short* la0 = ul + (n << 9) + kblk;
    const unsigned short* ua1 = uh + ((n + 16) << 9) + kblk;
    const unsigned short* la1 = ul + ((n + 16) << 9) + kblk;

#pragma unroll 1
    for (int rep = 0; rep < REP; ++rep) {
        asm volatile("" ::: "memory");
        f32x4 acc0 = {0.f, 0.f, 0.f, 0.f};
        f32x4 acc1 = {0.f, 0.f, 0.f, 0.f};
#pragma unroll 4
        for (int kt = 0; kt < 16; ++kt) {
            const int ko = kt * 32;
            const float4 x0 = *reinterpret_cast<const float4*>(Crow + ko);
            const float4 x1 = *reinterpret_cast<const float4*>(Crow + ko + 4);
            float v[8] = {x0.x, x0.y, x0.z, x0.w, x1.x, x1.y, x1.z, x1.w};
            union { bf16x8 v8; unsigned u4[4]; } H, L;
#pragma unroll
            for (int i = 0; i < 4; ++i) {
                const unsigned short h0 = f2bf(v[2 * i]), h1 = f2bf(v[2 * i + 1]);
                const unsigned short l0 = f2bf(v[2 * i] - bf2f(h0));
                const unsigned short l1 = f2bf(v[2 * i + 1] - bf2f(h1));
                H.u4[i] = (unsigned)h0 | ((unsigned)h1 << 16);
                L.u4[i] = (unsigned)l0 | ((unsigned)l1 << 16);
            }
            const bf16x8 bh = H.v8, bl = L.v8;
            const bf16x8 ah0 = *reinterpret_cast<const bf16x8*>(ua0 + ko);
            const bf16x8 al0 = *reinterpret_cast<const bf16x8*>(la0 + ko);
            const bf16x8 ah1 = *reinterpret_cast<const bf16x8*>(ua1 + ko);
            const bf16x8 al1 = *reinterpret_cast<const bf16x8*>(la1 + ko);
            acc0 = __builtin_amdgcn_mfma_f32_16x16x32_bf16(ah0, bh, acc0, 0, 0, 0);
            acc0 = __builtin_amdgcn_mfma_f32_16x16x32_bf16(ah0, bl, acc0, 0, 0, 0);
            acc0 = __builtin_amdgcn_mfma_f32_16x16x32_bf16(al0, bh, acc0, 0, 0, 0);
            acc1 = __builtin_amdgcn_mfma_f32_16x16x32_bf16(ah1, bh, acc1, 0, 0, 0);
            acc1 = __builtin_amdgcn_mfma_f32_16x16x32_bf16(ah1, bl, acc1, 0, 0, 0);
            acc1 = __builtin_amdgcn_mfma_f32_16x16x32_bf16(al1, bh, acc1, 0, 0, 0);
        }
        const int r0 = (lane >> 4) << 2;
#pragma unroll
        for (int r = 0; r < 4; ++r) {
            D[(size_t)(r0 + r) * NV + vrow]      = acc0[r];
            D[(size_t)(16 + r0 + r) * NV + vrow] = acc1[r];
        }
    }
}

// ---------------------------------------------------------------------------
// scores + softmax (rep region) + w-scatter (once, non-idempotent).
// ---------------------------------------------------------------------------
__global__ __launch_bounds__(256)
void scores_kernel(const float* __restrict__ D,
                   const int* __restrict__ inputs,
                   const int* __restrict__ lengths,
                   float* __restrict__ attn_out,   // [32][128]
                   float* __restrict__ w) {        // [32][NV], pre-zeroed
    const int b = blockIdx.x, tid = threadIdx.x;
    __shared__ float red[2];
    int idx[NL];
    float a = 0.f;
    if (tid < NM) {
        const int4* ip = reinterpret_cast<const int4*>(
            inputs + (((b << 7) + tid) << 5));
#pragma unroll
        for (int q = 0; q < 8; ++q) {
            const int4 i4 = ip[q];
            idx[q * 4 + 0] = i4.x; idx[q * 4 + 1] = i4.y;
            idx[q * 4 + 2] = i4.z; idx[q * 4 + 3] = i4.w;
        }
    }
#pragma unroll 1
    for (int rep = 0; rep < REP; ++rep) {
        asm volatile("" ::: "memory");
        float s = NEG_INF;
        if (tid < NM) {
            const float* Db = D + (size_t)b * NV;
            float acc = 0.f;
#pragma unroll
            for (int l = 0; l < NL; ++l) acc += Db[idx[l]];
            s = (lengths[(b << 7) + tid] == 0) ? NEG_INF : acc;
        }
        float mx = s;
#pragma unroll
        for (int o = 32; o; o >>= 1) mx = fmaxf(mx, __shfl_xor(mx, o, 64));
        if (tid < NM && (tid & 63) == 0) red[tid >> 6] = mx;
        __syncthreads();
        mx = fmaxf(red[0], red[1]);
        const float ee = (tid < NM) ? expf(s - mx) : 0.f;
        float sum = ee;
#pragma unroll
        for (int o = 32; o; o >>= 1) sum += __shfl_xor(sum, o, 64);
        __syncthreads();
        if (tid < NM && (tid & 63) == 0) red[tid >> 6] = sum;
        __syncthreads();
        a = ee / (red[0] + red[1]);
        if (tid < NM) attn_out[(b << 7) + tid] = a;
        __syncthreads();
    }
    if (tid < NM) {                       // non-idempotent: exactly once
        float* wb = w + (size_t)b * NV;
#pragma unroll
        for (int l = 0; l < NL; ++l) atomicAdd(&wb[idx[l]], a);
    }
}

// ---------------------------------------------------------------------------
// gemm_U (split-K): rep region; w-zeroing once after.
// ---------------------------------------------------------------------------
__global__ __launch_bounds__(512)
void gemm_U_kernel(float* __restrict__ w,
                   const float* __restrict__ Cn,
                   float* __restrict__ part,       // [NPART][32][512]
                   int zero_w) {
    const int tid = threadIdx.x;
    const int vbase = blockIdx.x * VC_U;
    const float* Cp = Cn + ((size_t)vbase << 9) + tid;

#pragma unroll 1
    for (int rep = 0; rep < REP; ++rep) {
        asm volatile("" ::: "memory");
        float acc[NB];
#pragma unroll
        for (int b = 0; b < NB; ++b) acc[b] = 0.f;
        for (int v = 0; v < VC_U; v += 4) {
            const float c0 = Cp[(size_t)(v + 0) << 9];
            const float c1 = Cp[(size_t)(v + 1) << 9];
            const float c2 = Cp[(size_t)(v + 2) << 9];
            const float c3 = Cp[(size_t)(v + 3) << 9];
#pragma unroll
            for (int b = 0; b < NB; ++b) {
                const float4 wv4 = *reinterpret_cast<const float4*>(
                    w + (size_t)b * NV + vbase + v);          // wave-uniform
                acc[b] += wv4.x * c0 + wv4.y * c1 + wv4.z * c2 + wv4.w * c3;
            }
        }
        float* pb = part + (size_t)blockIdx.x * (NB * NH);
#pragma unroll
        for (int b = 0; b < NB; ++b) pb[(b << 9) + tid] = acc[b];
    }

    if (zero_w) {
        __syncthreads();                     // all w reads done
        for (int i = tid; i < NB * VC_U; i += 512) {
            const int b = i >> 7, v = i & 127;
            w[(size_t)b * NV + vbase + v] = 0.f;
        }
    }
}

// ---------------------------------------------------------------------------
// reduce partials + u_in -> u_next; fused bf16 hi/lo split. rep-wrapped.
// ---------------------------------------------------------------------------
__global__ __launch_bounds__(256)
void reduce_u_kernel(const float* __restrict__ u_in,
                     const float* __restrict__ part,
                     float* __restrict__ u_out,
                     unsigned short* __restrict__ uh,
                     unsigned short* __restrict__ ul) {
    const int j = threadIdx.x & 63, q = threadIdx.x >> 6;
    const int e = blockIdx.x * 64 + j;
    const int p0 = (q * NPART) >> 2, p1 = ((q + 1) * NPART) >> 2;
    __shared__ float red[4][64];
#pragma unroll 1
    for (int rep = 0; rep < REP; ++rep) {
        asm volatile("" ::: "memory");
        float s = 0.f;
#pragma unroll 4
        for (int p = p0; p < p1; ++p) s += part[(size_t)p * (NB * NH) + e];
        red[q][j] = s;
        __syncthreads();
        if (threadIdx.x < 64) {
            const float t = u_in[e] + red[0][j] + red[1][j] + red[2][j] + red[3][j];
            u_out[e] = t;
            const unsigned short h = f2bf(t);
            uh[e] = h;
            ul[e] = f2bf(t - bf2f(h));
        }
        __syncthreads();
    }
}

// ---------------------------------------------------------------------------
// Tiny-workspace fallback (known-good gather path).
// ---------------------------------------------------------------------------
__global__ __launch_bounds__(128)
void scores_gather_kernel(const int* __restrict__ inputs,
                          const float* __restrict__ Ctab,
                          const float* __restrict__ u_in,
                          const int* __restrict__ lengths,
                          float* __restrict__ scores) {
    const int bm = blockIdx.x;
    const int b = bm / NM;
    const int tid = threadIdx.x;
    __shared__ int idx[NL];
    if (tid < NL) idx[tid] = inputs[bm * NL + tid];
    __syncthreads();
    const int hoff = tid * 4;
    const float4 u4 = *reinterpret_cast<const float4*>(u_in + b * NH + hoff);
    float p = 0.f;
    for (int l = 0; l < NL; ++l) {
        const float4 v = *reinterpret_cast<const float4*>(
            Ctab + (size_t)idx[l] * NH + hoff);
        p += u4.x * v.x + u4.y * v.y + u4.z * v.z + u4.w * v.w;
    }
#pragma unroll
    for (int off = 32; off; off >>= 1) p += __shfl_down(p, off, 64);
    __shared__ float w2[2];
    if ((tid & 63) == 0) w2[tid >> 6] = p;
    __syncthreads();
    if (tid == 0) {
        float sres = w2[0] + w2[1];
        if (lengths[bm] == 0) sres = NEG_INF;
        scores[bm] = sres;
    }
}

__global__ __launch_bounds__(128)
void softmax_kernel(const float* __restrict__ scores,
                    float* __restrict__ attn_ws,
                    float* __restrict__ attn_out) {
    const int b = blockIdx.x;
    const int tid = threadIdx.x;
    const float s = scores[b * NM + tid];
    float p = s;
#pragma unroll
    for (int off = 32; off; off >>= 1) p = fmaxf(p, __shfl_down(p, off, 64));
    __shared__ float w2[2];
    if ((tid & 63) == 0) w2[tid >> 6] = p;
    __syncthreads();
    const float mx = fmaxf(w2[0], w2[1]);
    const float e = expf(s - mx);
    float q = e;
#pragma unroll
    for (int off = 32; off; off >>= 1) q += __shfl_down(q, off, 64);
    __shared__ float w3[2];
    if ((tid & 63) == 0) w3[tid >> 6] = q;
    __syncthreads();
    const float a = e / (w3[0] + w3[1]);
    attn_ws[b * NM + tid] = a;
    attn_out[b * NM + tid] = a;
}

__global__ __launch_bounds__(512)
void update_gather_kernel(const int* __restrict__ inputs,
                          const float* __restrict__ Ctab,
                          const float* __restrict__ u_in,
                          const float* __restrict__ attn,
                          float* __restrict__ u_out) {
    const int b = blockIdx.x;
    const int tid = threadIdx.x;
    __shared__ float a_s[NM];
    __shared__ int idx_s[NM * NL];
    if (tid < NM) a_s[tid] = attn[b * NM + tid];
    for (int i = tid; i < NM * NL; i += 512) idx_s[i] = inputs[b * NM * NL + i];
    __syncthreads();
    float acc = u_in[b * NH + tid];
    for (int m = 0; m < NM; ++m) {
        const float a = a_s[m];
        float part = 0.f;
        for (int l = 0; l < NL; ++l) {
            part += Ctab[(size_t)idx_s[m * NL + l] * NH + tid];
        }
        acc += a * part;
    }
    u_out[b * NH + tid] = acc;
}

static void launch_fallback(const int* inputs, const int* lengths,
                            const float* enc, const float* C,
                            float* out, float* ws, hipStream_t stream) {
    const size_t TAB = (size_t)NV * NH;
    const size_t UE  = (size_t)NB * NH;
    float* scores  = ws;
    float* attn_ws = ws + NB * NM;
    float* u1      = attn_ws + NB * NM;
    float* u2      = u1 + UE;
    float* attns   = out + NB * NH;
    const float* uin = enc;
    float* uou[NHOPS] = {u1, u2, out};
    for (int h = 0; h < NHOPS; ++h) {
        scores_gather_kernel<<<NB * NM, 128, 0, stream>>>(
            inputs, C + (size_t)h * TAB, uin, lengths, scores);
        softmax_kernel<<<NB, 128, 0, stream>>>(
            scores, attn_ws, attns + (size_t)h * NB * NM);
        update_gather_kernel<<<NB, 512, 0, stream>>>(
            inputs, C + (size_t)(h + 1) * TAB, uin, attn_ws, uou[h]);
        uin = uou[h];
    }
}

// ---------------------------------------------------------------------------
extern "C" void kernel_launch(void* const* d_in, const int* in_sizes, int n_in,
                              void* d_out, int out_size, void* d_ws, size_t ws_size,
                              hipStream_t stream) {
    const int*   inputs  = (const int*)d_in[0];
    const int*   lengths = (const int*)d_in[1];
    const float* enc     = (const float*)d_in[2];
    const float* C       = (const float*)d_in[3];

    float* out   = (float*)d_out;
    float* attns = out + NB * NH;

    const size_t TAB = (size_t)NV * NH;
    const size_t BV  = (size_t)NB * NV;     // 1,024,000
    const size_t UE  = (size_t)NB * NH;     // 16,384
    float* ws = (float*)d_ws;

    const size_t need_f = 2 * BV + (size_t)NPART * UE + 2 * UE + UE;
    if (ws_size >= need_f * sizeof(float)) {
        float* D    = ws;
        float* w    = D + BV;
        float* part = w + BV;
        float* u1   = part + (size_t)NPART * UE;
        float* u2   = u1 + UE;
        unsigned short* uh = (unsigned short*)(u2 + UE);
        unsigned short* ul = uh + UE;

        init_kernel<<<256, 256, 0, stream>>>(enc, w, uh, ul);
        const float* uin[NHOPS]   = {enc, u1, u2};
        float*       unext[NHOPS] = {u1, u2, out};
        for (int h = 0; h < NHOPS; ++h) {
            gemm_D_kernel<<<NV / 64, 256, 0, stream>>>(
                uh, ul, C + (size_t)h * TAB, D);
            scores_kernel<<<NB, 256, 0, stream>>>(
                D, inputs, lengths, attns + (size_t)h * NB * NM, w);
            gemm_U_kernel<<<NPART, 512, 0, stream>>>(
                w, C + (size_t)(h + 1) * TAB, part, h < NHOPS - 1 ? 1 : 0);
            reduce_u_kernel<<<256, 256, 0, stream>>>(
                uin[h], part, unext[h], uh, ul);
        }
    } else {
        launch_fallback(inputs, lengths, enc, C, out, ws, stream);
    }
}

// Round 9
// 451.179 us; speedup vs baseline: 12.6116x; 12.6116x over previous
//
#include <hip/hip_runtime.h>

#define NB 32
#define NM 128
#define NL 32
#define NH 512
#define NV 32000
#define NHOPS 3
#define NEG_INF -1e9f

#define VC_U 64
#define NPART (NV / VC_U)       // 500 split-K partials

typedef __attribute__((ext_vector_type(8))) short bf16x8;
typedef __attribute__((ext_vector_type(4))) float f32x4;

__device__ __forceinline__ unsigned short f2bf(float x) {
    unsigned u = __float_as_uint(x);
    return (unsigned short)((u + 0x7fffu + ((u >> 16) & 1u)) >> 16);
}
__device__ __forceinline__ float bf2f(unsigned short h) {
    return __uint_as_float(((unsigned)h) << 16);
}

// ---------------------------------------------------------------------------
// init: zero w; split enc -> uh/ul.
// ---------------------------------------------------------------------------
__global__ __launch_bounds__(256)
void init_kernel(const float* __restrict__ enc, float* __restrict__ w,
                 unsigned short* __restrict__ uh, unsigned short* __restrict__ ul) {
    const int gtid = blockIdx.x * 256 + threadIdx.x;     // 65536 threads
    float4* w4 = reinterpret_cast<float4*>(w);
    for (int i = gtid; i < (NB * NV) / 4; i += 256 * 256)
        w4[i] = make_float4(0.f, 0.f, 0.f, 0.f);
    if (gtid < NB * NH) {
        const float x = enc[gtid];
        const unsigned short h = f2bf(x);
        uh[gtid] = h;
        ul[gtid] = f2bf(x - bf2f(h));
    }
}

// ---------------------------------------------------------------------------
// gemm_D: D[b][v] = u[b].C[v]  (M=32, N=32000, K=512), split-bf16, NO LDS.
// Validated ~6-10us (R8 diagnostic: absent from top-5 at REP=16).
// ---------------------------------------------------------------------------
__global__ __launch_bounds__(256)
void gemm_D_kernel(const unsigned short* __restrict__ uh,
                   const unsigned short* __restrict__ ul,
                   const float* __restrict__ Ct,
                   float* __restrict__ D) {
    const int tid = threadIdx.x;
    const int wv = tid >> 6, lane = tid & 63;
    const int n = lane & 15;
    const int kblk = (lane >> 4) << 3;
    const int vrow = (blockIdx.x * 4 + wv) * 16 + n;

    const float* Crow = Ct + ((size_t)vrow << 9) + kblk;
    const unsigned short* ua0 = uh + (n << 9) + kblk;
    const unsigned short* la0 = ul + (n << 9) + kblk;
    const unsigned short* ua1 = uh + ((n + 16) << 9) + kblk;
    const unsigned short* la1 = ul + ((n + 16) << 9) + kblk;

    f32x4 acc0 = {0.f, 0.f, 0.f, 0.f};
    f32x4 acc1 = {0.f, 0.f, 0.f, 0.f};

#pragma unroll 4
    for (int kt = 0; kt < 16; ++kt) {
        const int ko = kt * 32;
        const float4 x0 = *reinterpret_cast<const float4*>(Crow + ko);
        const float4 x1 = *reinterpret_cast<const float4*>(Crow + ko + 4);
        float v[8] = {x0.x, x0.y, x0.z, x0.w, x1.x, x1.y, x1.z, x1.w};
        union { bf16x8 v8; unsigned u4[4]; } H, L;
#pragma unroll
        for (int i = 0; i < 4; ++i) {
            const unsigned short h0 = f2bf(v[2 * i]), h1 = f2bf(v[2 * i + 1]);
            const unsigned short l0 = f2bf(v[2 * i] - bf2f(h0));
            const unsigned short l1 = f2bf(v[2 * i + 1] - bf2f(h1));
            H.u4[i] = (unsigned)h0 | ((unsigned)h1 << 16);
            L.u4[i] = (unsigned)l0 | ((unsigned)l1 << 16);
        }
        const bf16x8 bh = H.v8, bl = L.v8;
        const bf16x8 ah0 = *reinterpret_cast<const bf16x8*>(ua0 + ko);
        const bf16x8 al0 = *reinterpret_cast<const bf16x8*>(la0 + ko);
        const bf16x8 ah1 = *reinterpret_cast<const bf16x8*>(ua1 + ko);
        const bf16x8 al1 = *reinterpret_cast<const bf16x8*>(la1 + ko);
        acc0 = __builtin_amdgcn_mfma_f32_16x16x32_bf16(ah0, bh, acc0, 0, 0, 0);
        acc0 = __builtin_amdgcn_mfma_f32_16x16x32_bf16(ah0, bl, acc0, 0, 0, 0);
        acc0 = __builtin_amdgcn_mfma_f32_16x16x32_bf16(al0, bh, acc0, 0, 0, 0);
        acc1 = __builtin_amdgcn_mfma_f32_16x16x32_bf16(ah1, bh, acc1, 0, 0, 0);
        acc1 = __builtin_amdgcn_mfma_f32_16x16x32_bf16(ah1, bl, acc1, 0, 0, 0);
        acc1 = __builtin_amdgcn_mfma_f32_16x16x32_bf16(al1, bh, acc1, 0, 0, 0);
    }
    const int r0 = (lane >> 4) << 2;
#pragma unroll
    for (int r = 0; r < 4; ++r) {
        D[(size_t)(r0 + r) * NV + vrow]      = acc0[r];
        D[(size_t)(16 + r0 + r) * NV + vrow] = acc1[r];
    }
}

// ---------------------------------------------------------------------------
// scores + softmax + w-scatter: one block per b (256 thr; tid<128 = m).
// ---------------------------------------------------------------------------
__global__ __launch_bounds__(256)
void scores_kernel(const float* __restrict__ D,
                   const int* __restrict__ inputs,
                   const int* __restrict__ lengths,
                   float* __restrict__ attn_out,   // [32][128]
                   float* __restrict__ w) {        // [32][NV], pre-zeroed
    const int b = blockIdx.x, tid = threadIdx.x;
    int idx[NL];
    float s = NEG_INF;
    if (tid < NM) {
        const int4* ip = reinterpret_cast<const int4*>(
            inputs + (((b << 7) + tid) << 5));
        const float* Db = D + (size_t)b * NV;
        float acc = 0.f;
#pragma unroll
        for (int q = 0; q < 8; ++q) {
            const int4 i4 = ip[q];
            idx[q * 4 + 0] = i4.x; idx[q * 4 + 1] = i4.y;
            idx[q * 4 + 2] = i4.z; idx[q * 4 + 3] = i4.w;
        }
#pragma unroll
        for (int l = 0; l < NL; ++l) acc += Db[idx[l]];
        s = (lengths[(b << 7) + tid] == 0) ? NEG_INF : acc;
    }
    __shared__ float red[2];
    float mx = s;
#pragma unroll
    for (int o = 32; o; o >>= 1) mx = fmaxf(mx, __shfl_xor(mx, o, 64));
    if (tid < NM && (tid & 63) == 0) red[tid >> 6] = mx;
    __syncthreads();
    mx = fmaxf(red[0], red[1]);
    const float ee = (tid < NM) ? expf(s - mx) : 0.f;
    float sum = ee;
#pragma unroll
    for (int o = 32; o; o >>= 1) sum += __shfl_xor(sum, o, 64);
    __syncthreads();
    if (tid < NM && (tid & 63) == 0) red[tid >> 6] = sum;
    __syncthreads();
    if (tid < NM) {
        const float a = ee / (red[0] + red[1]);
        attn_out[(b << 7) + tid] = a;
        float* wb = w + (size_t)b * NV;
#pragma unroll
        for (int l = 0; l < NL; ++l) atomicAdd(&wb[idx[l]], a);
    }
}

// ---------------------------------------------------------------------------
// gemm_U v2 (split-K): part[blk][b][h] = sum_{v in 64-chunk} w[b][v]*C[v][h]
// 500 blocks x 512 thr (2 blocks/CU, 16 waves/CU -- 2x the TLP of R8's 250x512).
// w is const __restrict__ with wave-uniform addresses -> scalarizable to
// s_load (SMEM pipe, parallel to VMEM). v unrolled x8: 8 independent strided
// C loads in flight per step. w-zeroing moved to reduce_u to keep w const.
// ---------------------------------------------------------------------------
__global__ __launch_bounds__(512)
void gemm_U_kernel(const float* __restrict__ w,
                   const float* __restrict__ Cn,
                   float* __restrict__ part) {     // [NPART][32][512]
    const int tid = threadIdx.x;
    const int vbase = blockIdx.x * VC_U;
    const float* Cp = Cn + ((size_t)vbase << 9) + tid;
    const float* wp = w + vbase;

    float acc[NB];
#pragma unroll
    for (int b = 0; b < NB; ++b) acc[b] = 0.f;

#pragma unroll 2
    for (int v0 = 0; v0 < VC_U; v0 += 8) {
        float c[8];
#pragma unroll
        for (int i = 0; i < 8; ++i)
            c[i] = Cp[(size_t)(v0 + i) << 9];          // 8 independent loads
#pragma unroll
        for (int b = 0; b < NB; ++b) {
            const float4 wa = *reinterpret_cast<const float4*>(
                wp + (size_t)b * NV + v0);             // wave-uniform
            const float4 wb = *reinterpret_cast<const float4*>(
                wp + (size_t)b * NV + v0 + 4);
            acc[b] += wa.x * c[0] + wa.y * c[1] + wa.z * c[2] + wa.w * c[3]
                    + wb.x * c[4] + wb.y * c[5] + wb.z * c[6] + wb.w * c[7];
        }
    }
    float* pb = part + (size_t)blockIdx.x * (NB * NH);
#pragma unroll
    for (int b = 0; b < NB; ++b) pb[(b << 9) + tid] = acc[b];
}

// ---------------------------------------------------------------------------
// reduce partials (4-way q-split over 500) + u_in -> u_next; fused bf16 split;
// optionally re-zeroes w for the next hop's scatter (after U has read it).
// grid 256 x 256; block covers 64 elements.
// ---------------------------------------------------------------------------
__global__ __launch_bounds__(256)
void reduce_u_kernel(const float* __restrict__ u_in,
                     const float* __restrict__ part,
                     float* __restrict__ u_out,
                     unsigned short* __restrict__ uh,
                     unsigned short* __restrict__ ul,
                     float* __restrict__ w, int zero_w) {
    const int j = threadIdx.x & 63, q = threadIdx.x >> 6;
    const int e = blockIdx.x * 64 + j;
    const int p0 = (q * NPART) >> 2, p1 = ((q + 1) * NPART) >> 2;
    float s = 0.f;
#pragma unroll 5
    for (int p = p0; p < p1; ++p) s += part[(size_t)p * (NB * NH) + e];
    __shared__ float red[4][64];
    red[q][j] = s;
    __syncthreads();
    if (threadIdx.x < 64) {
        const float t = u_in[e] + red[0][j] + red[1][j] + red[2][j] + red[3][j];
        u_out[e] = t;
        const unsigned short h = f2bf(t);
        uh[e] = h;
        ul[e] = f2bf(t - bf2f(h));
    }
    if (zero_w) {
        const int gtid = blockIdx.x * 256 + threadIdx.x;   // 65536 threads
        float4* w4 = reinterpret_cast<float4*>(w);
#pragma unroll
        for (int i = 0; i < 4; ++i)                        // 4 f4 per thread
            w4[gtid + i * 65536] = make_float4(0.f, 0.f, 0.f, 0.f);
    }
}

// ---------------------------------------------------------------------------
// Tiny-workspace fallback (known-good gather path).
// ---------------------------------------------------------------------------
__global__ __launch_bounds__(128)
void scores_gather_kernel(const int* __restrict__ inputs,
                          const float* __restrict__ Ctab,
                          const float* __restrict__ u_in,
                          const int* __restrict__ lengths,
                          float* __restrict__ scores) {
    const int bm = blockIdx.x;
    const int b = bm / NM;
    const int tid = threadIdx.x;
    __shared__ int idx[NL];
    if (tid < NL) idx[tid] = inputs[bm * NL + tid];
    __syncthreads();
    const int hoff = tid * 4;
    const float4 u4 = *reinterpret_cast<const float4*>(u_in + b * NH + hoff);
    float p = 0.f;
    for (int l = 0; l < NL; ++l) {
        const float4 v = *reinterpret_cast<const float4*>(
            Ctab + (size_t)idx[l] * NH + hoff);
        p += u4.x * v.x + u4.y * v.y + u4.z * v.z + u4.w * v.w;
    }
#pragma unroll
    for (int off = 32; off; off >>= 1) p += __shfl_down(p, off, 64);
    __shared__ float w2[2];
    if ((tid & 63) == 0) w2[tid >> 6] = p;
    __syncthreads();
    if (tid == 0) {
        float sres = w2[0] + w2[1];
        if (lengths[bm] == 0) sres = NEG_INF;
        scores[bm] = sres;
    }
}

__global__ __launch_bounds__(128)
void softmax_kernel(const float* __restrict__ scores,
                    float* __restrict__ attn_ws,
                    float* __restrict__ attn_out) {
    const int b = blockIdx.x;
    const int tid = threadIdx.x;
    const float s = scores[b * NM + tid];
    float p = s;
#pragma unroll
    for (int off = 32; off; off >>= 1) p = fmaxf(p, __shfl_down(p, off, 64));
    __shared__ float w2[2];
    if ((tid & 63) == 0) w2[tid >> 6] = p;
    __syncthreads();
    const float mx = fmaxf(w2[0], w2[1]);
    const float e = expf(s - mx);
    float q = e;
#pragma unroll
    for (int off = 32; off; off >>= 1) q += __shfl_down(q, off, 64);
    __shared__ float w3[2];
    if ((tid & 63) == 0) w3[tid >> 6] = q;
    __syncthreads();
    const float a = e / (w3[0] + w3[1]);
    attn_ws[b * NM + tid] = a;
    attn_out[b * NM + tid] = a;
}

__global__ __launch_bounds__(512)
void update_gather_kernel(const int* __restrict__ inputs,
                          const float* __restrict__ Ctab,
                          const float* __restrict__ u_in,
                          const float* __restrict__ attn,
                          float* __restrict__ u_out) {
    const int b = blockIdx.x;
    const int tid = threadIdx.x;
    __shared__ float a_s[NM];
    __shared__ int idx_s[NM * NL];
    if (tid < NM) a_s[tid] = attn[b * NM + tid];
    for (int i = tid; i < NM * NL; i += 512) idx_s[i] = inputs[b * NM * NL + i];
    __syncthreads();
    float acc = u_in[b * NH + tid];
    for (int m = 0; m < NM; ++m) {
        const float a = a_s[m];
        float part = 0.f;
        for (int l = 0; l < NL; ++l) {
            part += Ctab[(size_t)idx_s[m * NL + l] * NH + tid];
        }
        acc += a * part;
    }
    u_out[b * NH + tid] = acc;
}

static void launch_fallback(const int* inputs, const int* lengths,
                            const float* enc, const float* C,
                            float* out, float* ws, hipStream_t stream) {
    const size_t TAB = (size_t)NV * NH;
    const size_t UE  = (size_t)NB * NH;
    float* scores  = ws;
    float* attn_ws = ws + NB * NM;
    float* u1      = attn_ws + NB * NM;
    float* u2      = u1 + UE;
    float* attns   = out + NB * NH;
    const float* uin = enc;
    float* uou[NHOPS] = {u1, u2, out};
    for (int h = 0; h < NHOPS; ++h) {
        scores_gather_kernel<<<NB * NM, 128, 0, stream>>>(
            inputs, C + (size_t)h * TAB, uin, lengths, scores);
        softmax_kernel<<<NB, 128, 0, stream>>>(
            scores, attn_ws, attns + (size_t)h * NB * NM);
        update_gather_kernel<<<NB, 512, 0, stream>>>(
            inputs, C + (size_t)(h + 1) * TAB, uin, attn_ws, uou[h]);
        uin = uou[h];
    }
}

// ---------------------------------------------------------------------------
extern "C" void kernel_launch(void* const* d_in, const int* in_sizes, int n_in,
                              void* d_out, int out_size, void* d_ws, size_t ws_size,
                              hipStream_t stream) {
    const int*   inputs  = (const int*)d_in[0];
    const int*   lengths = (const int*)d_in[1];
    const float* enc     = (const float*)d_in[2];
    const float* C       = (const float*)d_in[3];

    float* out   = (float*)d_out;
    float* attns = out + NB * NH;

    const size_t TAB = (size_t)NV * NH;
    const size_t BV  = (size_t)NB * NV;     // 1,024,000
    const size_t UE  = (size_t)NB * NH;     // 16,384
    float* ws = (float*)d_ws;

    const size_t need_f = 2 * BV + (size_t)NPART * UE + 2 * UE + UE;
    if (ws_size >= need_f * sizeof(float)) {
        float* D    = ws;
        float* w    = D + BV;
        float* part = w + BV;
        float* u1   = part + (size_t)NPART * UE;
        float* u2   = u1 + UE;
        unsigned short* uh = (unsigned short*)(u2 + UE);
        unsigned short* ul = uh + UE;

        init_kernel<<<256, 256, 0, stream>>>(enc, w, uh, ul);
        const float* uin[NHOPS]   = {enc, u1, u2};
        float*       unext[NHOPS] = {u1, u2, out};
        for (int h = 0; h < NHOPS; ++h) {
            gemm_D_kernel<<<NV / 64, 256, 0, stream>>>(
                uh, ul, C + (size_t)h * TAB, D);
            scores_kernel<<<NB, 256, 0, stream>>>(
                D, inputs, lengths, attns + (size_t)h * NB * NM, w);
            gemm_U_kernel<<<NPART, 512, 0, stream>>>(
                w, C + (size_t)(h + 1) * TAB, part);
            reduce_u_kernel<<<256, 256, 0, stream>>>(
                uin[h], part, unext[h], uh, ul, w, h < NHOPS - 1 ? 1 : 0);
        }
    } else {
        launch_fallback(inputs, lengths, enc, C, out, ws, stream);
    }
}